// Round 3
// baseline (226.681 us; speedup 1.0000x reference)
//
#include <hip/hip_runtime.h>
#include <hip/hip_bf16.h>

// MultiHeadAttention: B=4 S=2048 D=1024 H=16 DK=DV=64 scale=8
// R3: proj fixes — (1) revert m240 mistake: staging conversion via compiler
// scalar casts (not inline-asm cvt_pk); (2) LDS double-buffer, ONE barrier per
// k-step, next-tile global loads issued right after the barrier (latency hides
// under ds_read+MFMA). Attn unchanged from R2 (69 us).

typedef unsigned short u16;
typedef unsigned int   u32;
typedef short bf16x8 __attribute__((ext_vector_type(8)));
typedef short bf16x4 __attribute__((ext_vector_type(4)));
typedef float f32x4  __attribute__((ext_vector_type(4)));
typedef u32   u32x4  __attribute__((ext_vector_type(4)));

#define S_TOT 2048
#define HD    1024
#define QK_SCALE 0.18033688f   // log2(e)/8

#if __has_builtin(__builtin_amdgcn_exp2f)
#define EXP2(x) __builtin_amdgcn_exp2f(x)
#else
#define EXP2(x) exp2f(x)
#endif

// compiler-cast f32 -> bf16 (m240: scalar cast beats hand-written cvt_pk asm)
__device__ __forceinline__ short f2bf_c(float f) {
  __hip_bfloat16 h = __float2bfloat16(f);
  return __builtin_bit_cast(short, h);
}

// attn keeps the packed asm form (T12 structural pack — measured win there)
__device__ __forceinline__ u32 cvt_pk_bf16(float lo, float hi) {
  u32 r;
  asm("v_cvt_pk_bf16_f32 %0, %1, %2" : "=v"(r) : "v"(lo), "v"(hi));
  return r;
}

__device__ __forceinline__ bf16x4 ds_tr16(unsigned a) {
  bf16x4 d;
  asm volatile("ds_read_b64_tr_b16 %0, %1" : "=v"(d) : "v"(a) : "memory");
  return d;
}

// rule #18: inline-asm lgkmcnt needs sched_barrier(0) right after
#define LGKM_FENCE() do { asm volatile("s_waitcnt lgkmcnt(0)" ::: "memory"); \
                          __builtin_amdgcn_sched_barrier(0); } while (0)

// ---------------------------------------------------------------------------
// Projection GEMM: out = bf16( scale * (X.W + bias) ), M=8192 N=1024 K=1024
// 128x128xBK32 tiles, 4 waves, wave tile 64x64. LDS double-buffered, one
// barrier per k-step, reg-staged with next-tile loads issued post-barrier.
// z==0 (q) folds log2e/8 into the output.
// ---------------------------------------------------------------------------
__global__ __launch_bounds__(256)
void proj_kernel(const float* __restrict__ x0, const float* __restrict__ x1, const float* __restrict__ x2,
                 const float* __restrict__ w0, const float* __restrict__ w1, const float* __restrict__ w2,
                 const float* __restrict__ b0, const float* __restrict__ b1, const float* __restrict__ b2,
                 u16* __restrict__ o0, u16* __restrict__ o1, u16* __restrict__ o2)
{
  // bijective XCD swizzle: nwg=1536 (%8==0)
  int p  = blockIdx.x + 8 * blockIdx.y + 512 * blockIdx.z;
  int wk = (p & 7) * 192 + (p >> 3);
  int nb = wk & 7, mb = (wk >> 3) & 63, z = wk >> 9;

  const float* X  = z == 0 ? x0 : (z == 1 ? x1 : x2);
  const float* W  = z == 0 ? w0 : (z == 1 ? w1 : w2);
  const float* BS = z == 0 ? b0 : (z == 1 ? b1 : b2);
  u16*         O  = z == 0 ? o0 : (z == 1 ? o1 : o2);
  const float  osc = (z == 0) ? QK_SCALE : 1.0f;

  const int t = threadIdx.x;
  const int lane = t & 63, wid = t >> 6;
  const int g = lane >> 4, ln = lane & 15;
  const int wm = wid >> 1, wn = wid & 1;
  const int mbase = mb * 128, nbase = nb * 128;

  // A: row-major, k-permuted (one b128 = one split-K fragment), stride 40 u16
  // B: [nblk8][kblk2] 16x16 k-major tiles, tile stride 272 u16, for tr-reads
  __shared__ __align__(16) u16 As[2][128 * 40];
  __shared__ __align__(16) u16 Bs[2][16 * 272];

  f32x4 acc[4][4];
#pragma unroll
  for (int i = 0; i < 4; ++i)
#pragma unroll
    for (int j = 0; j < 4; ++j) { acc[i][j][0]=0.f; acc[i][j][1]=0.f; acc[i][j][2]=0.f; acc[i][j][3]=0.f; }

  const int arow = t >> 3;                 // + 32*ps
  const int ak0  = (t & 7) * 4;
  const int ap   = 8 * ((ak0 & 15) >> 2) + 4 * (ak0 >> 4);
  const int bkr  = t >> 5;                 // + 8*ps
  const int bnc  = (t & 31) * 4;
  const int bnblk = bnc >> 4, bncl = bnc & 15;

  const unsigned bs_base0 = (unsigned)(size_t)&Bs[0][0];

  const float* xp = &X[(size_t)(mbase + arow) * 1024 + ak0];
  const float* wp = &W[(size_t)bkr * 1024 + nbase + bnc];

  // prologue: tile 0 into regs
  float4 xr[4], wr[4];
#pragma unroll
  for (int ps = 0; ps < 4; ++ps) {
    xr[ps] = *(const float4*)(xp + (size_t)(32 * ps) * 1024);
    wr[ps] = *(const float4*)(wp + (size_t)(8 * ps) * 1024);
  }

  for (int kb = 0; kb < 32; ++kb) {
    const int buf = kb & 1;
    // cvt + LDS write of tile kb (regs -> LDS)
#pragma unroll
    for (int ps = 0; ps < 4; ++ps) {
      bf16x4 av = { f2bf_c(xr[ps].x), f2bf_c(xr[ps].y), f2bf_c(xr[ps].z), f2bf_c(xr[ps].w) };
      *(bf16x4*)&As[buf][(arow + 32 * ps) * 40 + ap] = av;
      int kr = bkr + 8 * ps;
      bf16x4 bv = { f2bf_c(wr[ps].x), f2bf_c(wr[ps].y), f2bf_c(wr[ps].z), f2bf_c(wr[ps].w) };
      *(bf16x4*)&Bs[buf][(bnblk * 2 + (kr >> 4)) * 272 + (kr & 15) * 16 + bncl] = bv;
    }
    __syncthreads();
    // issue next tile's global loads; consumed at next iteration's top
    if (kb < 31) {
      xp += 32; wp += (size_t)32 * 1024;
#pragma unroll
      for (int ps = 0; ps < 4; ++ps) {
        xr[ps] = *(const float4*)(xp + (size_t)(32 * ps) * 1024);
        wr[ps] = *(const float4*)(wp + (size_t)(8 * ps) * 1024);
      }
    }

    bf16x8 af[4];
#pragma unroll
    for (int mf = 0; mf < 4; ++mf)
      af[mf] = *(const bf16x8*)&As[buf][(wm * 64 + mf * 16 + ln) * 40 + g * 8];

    bf16x8 bfv[4];
#pragma unroll
    for (int nf = 0; nf < 4; ++nf) {
      unsigned base = bs_base0 + (unsigned)(buf * (16 * 272 * 2))
                    + (unsigned)(((wn * 4 + nf) * 2) * 544) + lane * 8;
      bf16x4 lo = ds_tr16(base);         // k 0..15
      bf16x4 hi = ds_tr16(base + 544);   // k 16..31
      bf16x8 bb;
      bb[0]=lo[0]; bb[1]=lo[1]; bb[2]=lo[2]; bb[3]=lo[3];
      bb[4]=hi[0]; bb[5]=hi[1]; bb[6]=hi[2]; bb[7]=hi[3];
      bfv[nf] = bb;
    }
    LGKM_FENCE();
#pragma unroll
    for (int mf = 0; mf < 4; ++mf)
#pragma unroll
      for (int nf = 0; nf < 4; ++nf)
        acc[mf][nf] = __builtin_amdgcn_mfma_f32_16x16x32_bf16(af[mf], bfv[nf], acc[mf][nf], 0, 0, 0);
    // no second barrier: next iter writes buf^1; reuse of THIS buf is two
    // iterations away, separated by the next iteration's barrier.
  }

  // epilogue: bias + scale + bf16 store
#pragma unroll
  for (int nf = 0; nf < 4; ++nf) {
    int n = nbase + wn * 64 + nf * 16 + ln;
    float bv = BS[n];
#pragma unroll
    for (int mf = 0; mf < 4; ++mf)
#pragma unroll
      for (int r = 0; r < 4; ++r) {
        int m = mbase + wm * 64 + mf * 16 + 4 * g + r;
        O[(size_t)m * 1024 + n] = (u16)f2bf_c((acc[mf][nf][r] + bv) * osc);
      }
  }
}

// ---------------------------------------------------------------------------
// Attention (unchanged from R2): per block (b,h,qtile128), 4 waves x 32 q-rows,
// kv steps of 32. Swapped QK^T -> P feeds PV A-operand directly; max-free
// softmax (qh pre-scaled by log2e/8).
// ---------------------------------------------------------------------------
__global__ __launch_bounds__(256)
void attn_kernel(const u16* __restrict__ qh, const u16* __restrict__ kh, const u16* __restrict__ vh,
                 float* __restrict__ out)
{
  int p  = blockIdx.x + 16 * blockIdx.y + 256 * blockIdx.z;
  int wk = (p & 7) * 128 + (p >> 3);
  int qt = wk & 15, h = (wk >> 4) & 15, b = wk >> 8;

  const int t = threadIdx.x;
  const int lane = t & 63, wid = t >> 6;
  const int g = lane >> 4, ln = lane & 15;
  const size_t bS = (size_t)b * S_TOT;
  const int qwin = qt * 128 + wid * 32;

  __shared__ __align__(16) u16 Ks[32 * 72];
  __shared__ __align__(16) u16 Vs[8 * 272];

  bf16x8 qf[2][2];
#pragma unroll
  for (int nf = 0; nf < 2; ++nf) {
    const u16* qrow = &qh[(bS + qwin + nf * 16 + ln) * HD + h * 64];
#pragma unroll
    for (int kk = 0; kk < 2; ++kk) {
      bf16x4 lo = *(const bf16x4*)&qrow[kk * 32 + 4 * g];
      bf16x4 hi = *(const bf16x4*)&qrow[kk * 32 + 4 * g + 16];
      bf16x8 qq;
      qq[0]=lo[0]; qq[1]=lo[1]; qq[2]=lo[2]; qq[3]=lo[3];
      qq[4]=hi[0]; qq[5]=hi[1]; qq[6]=hi[2]; qq[7]=hi[3];
      qf[nf][kk] = qq;
    }
  }

  f32x4 o[2][4];
#pragma unroll
  for (int i = 0; i < 2; ++i)
#pragma unroll
    for (int j = 0; j < 4; ++j) { o[i][j][0]=0.f; o[i][j][1]=0.f; o[i][j][2]=0.f; o[i][j][3]=0.f; }
  float lsum[2] = {0.f, 0.f};

  const unsigned vs_base = (unsigned)(size_t)&Vs[0] + lane * 8;
  const int skv = t >> 4;
  const int sd0 = (t & 15) * 4;
  const int kpos = 32 * (sd0 >> 5) + 8 * ((sd0 & 15) >> 2) + 4 * ((sd0 >> 4) & 1);

  u16* ksw0 = &Ks[skv * 72 + kpos];
  u16* ksw1 = &Ks[(skv + 16) * 72 + kpos];
  u16* vsw0 = &Vs[(2 * (sd0 >> 4) + 0) * 272 + skv * 16 + (sd0 & 15)];
  u16* vsw1 = &Vs[(2 * (sd0 >> 4) + 1) * 272 + skv * 16 + (sd0 & 15)];
  const u16* kp = &kh[(bS + skv) * HD + h * 64 + sd0];
  const u16* vp = &vh[(bS + skv) * HD + h * 64 + sd0];

  for (int kvstep = 0; kvstep < 64; ++kvstep) {
    *(bf16x4*)ksw0 = *(const bf16x4*)kp;
    *(bf16x4*)ksw1 = *(const bf16x4*)(kp + (size_t)16 * HD);
    *(bf16x4*)vsw0 = *(const bf16x4*)vp;
    *(bf16x4*)vsw1 = *(const bf16x4*)(vp + (size_t)16 * HD);
    kp += (size_t)32 * HD; vp += (size_t)32 * HD;
    __syncthreads();

    bf16x8 kf[2][2];
#pragma unroll
    for (int mf = 0; mf < 2; ++mf)
#pragma unroll
      for (int kk = 0; kk < 2; ++kk)
        kf[mf][kk] = *(const bf16x8*)&Ks[(mf * 16 + ln) * 72 + kk * 32 + 8 * g];

    f32x4 sc[2][2];
#pragma unroll
    for (int mf = 0; mf < 2; ++mf)
#pragma unroll
      for (int nf = 0; nf < 2; ++nf) {
        f32x4 a; a[0]=0.f; a[1]=0.f; a[2]=0.f; a[3]=0.f;
#pragma unroll
        for (int kk = 0; kk < 2; ++kk)
          a = __builtin_amdgcn_mfma_f32_16x16x32_bf16(kf[mf][kk], qf[nf][kk], a, 0, 0, 0);
        sc[mf][nf] = a;
      }

    bf16x8 vf[4];
#pragma unroll
    for (int nf = 0; nf < 4; ++nf) {
      bf16x4 lo = ds_tr16(vs_base + (unsigned)((nf * 2) * 544));
      bf16x4 hi = ds_tr16(vs_base + (unsigned)((nf * 2 + 1) * 544));
      bf16x8 bb;
      bb[0]=lo[0]; bb[1]=lo[1]; bb[2]=lo[2]; bb[3]=lo[3];
      bb[4]=hi[0]; bb[5]=hi[1]; bb[6]=hi[2]; bb[7]=hi[3];
      vf[nf] = bb;
    }

    bf16x8 pa[2];
#pragma unroll
    for (int nf = 0; nf < 2; ++nf) {
      float pv[2][4];
#pragma unroll
      for (int mf = 0; mf < 2; ++mf)
#pragma unroll
        for (int r = 0; r < 4; ++r)
          pv[mf][r] = EXP2(sc[mf][nf][r]);
      float s0 = pv[0][0] + pv[0][1], s1 = pv[0][2] + pv[0][3];
      float s2 = pv[1][0] + pv[1][1], s3 = pv[1][2] + pv[1][3];
      lsum[nf] += (s0 + s1) + (s2 + s3);
      union { u32x4 u; bf16x8 b; } pk;
      pk.u[0] = cvt_pk_bf16(pv[0][0], pv[0][1]);
      pk.u[1] = cvt_pk_bf16(pv[0][2], pv[0][3]);
      pk.u[2] = cvt_pk_bf16(pv[1][0], pv[1][1]);
      pk.u[3] = cvt_pk_bf16(pv[1][2], pv[1][3]);
      pa[nf] = pk.b;
    }

    LGKM_FENCE();
#pragma unroll
    for (int mq = 0; mq < 2; ++mq)
#pragma unroll
      for (int nf = 0; nf < 4; ++nf)
        o[mq][nf] = __builtin_amdgcn_mfma_f32_16x16x32_bf16(pa[mq], vf[nf], o[mq][nf], 0, 0, 0);
    __syncthreads();
  }

#pragma unroll
  for (int nf = 0; nf < 2; ++nf) {
    lsum[nf] += __shfl_xor(lsum[nf], 16, 64);
    lsum[nf] += __shfl_xor(lsum[nf], 32, 64);
  }

#pragma unroll
  for (int mq = 0; mq < 2; ++mq)
#pragma unroll
    for (int r = 0; r < 4; ++r) {
      int src = (lane & 48) | (4 * g + r);
      float inv = 1.0f / __shfl(lsum[mq], src, 64);
      int qrow = qwin + mq * 16 + 4 * g + r;
#pragma unroll
      for (int nf = 0; nf < 4; ++nf)
        out[(bS + qrow) * HD + h * 64 + nf * 16 + ln] = o[mq][nf][r] * inv;
    }
}

extern "C" void kernel_launch(void* const* d_in, const int* in_sizes, int n_in,
                              void* d_out, int out_size, void* d_ws, size_t ws_size,
                              hipStream_t stream) {
  const float* q  = (const float*)d_in[0];
  const float* k  = (const float*)d_in[1];
  const float* v  = (const float*)d_in[2];
  const float* Wq = (const float*)d_in[3];
  const float* bq = (const float*)d_in[4];
  const float* Wk = (const float*)d_in[5];
  const float* bk = (const float*)d_in[6];
  const float* Wv = (const float*)d_in[7];
  const float* bv = (const float*)d_in[8];
  float* out = (float*)d_out;

  u16* qh = (u16*)d_ws;
  u16* kh = qh + (size_t)8192 * 1024;
  u16* vh = kh + (size_t)8192 * 1024;

  proj_kernel<<<dim3(8, 64, 3), 256, 0, stream>>>(q, k, v, Wq, Wk, Wv, bq, bk, bv, qh, kh, vh);
  attn_kernel<<<dim3(16, 16, 4), 256, 0, stream>>>(qh, kh, vh, out);
}

// Round 4
// 216.106 us; speedup vs baseline: 1.0489x; 1.0489x over previous
//
#include <hip/hip_runtime.h>
#include <hip/hip_bf16.h>

// MultiHeadAttention: B=4 S=2048 D=1024 H=16 DK=DV=64 scale=8
// R4: proj = R1's proven single-buffer 2-barrier structure (86 us) with ONE
// change: staging/epilogue fp32->bf16 via compiler __float2bfloat16 cast
// (m240: compiler handles cvt; manual asm cvt_pk was -41%, manual RNE ~4 ops).
// Attn unchanged from R2 (66 us, ~1.04 PF effective).

typedef unsigned short u16;
typedef unsigned int   u32;
typedef short bf16x8 __attribute__((ext_vector_type(8)));
typedef short bf16x4 __attribute__((ext_vector_type(4)));
typedef float f32x4  __attribute__((ext_vector_type(4)));
typedef u32   u32x4  __attribute__((ext_vector_type(4)));

#define S_TOT 2048
#define HD    1024
#define QK_SCALE 0.18033688f   // log2(e)/8

#if __has_builtin(__builtin_amdgcn_exp2f)
#define EXP2(x) __builtin_amdgcn_exp2f(x)
#else
#define EXP2(x) exp2f(x)
#endif

// compiler-cast f32 -> bf16 (RNE); let the scheduler/packer handle it (m240)
__device__ __forceinline__ short f2bf_c(float f) {
  __hip_bfloat16 h = __float2bfloat16(f);
  return __builtin_bit_cast(short, h);
}

// attn keeps the packed asm form (T12 structural pack — measured win there)
__device__ __forceinline__ u32 cvt_pk_bf16(float lo, float hi) {
  u32 r;
  asm("v_cvt_pk_bf16_f32 %0, %1, %2" : "=v"(r) : "v"(lo), "v"(hi));
  return r;
}

__device__ __forceinline__ bf16x4 ds_tr16(unsigned a) {
  bf16x4 d;
  asm volatile("ds_read_b64_tr_b16 %0, %1" : "=v"(d) : "v"(a) : "memory");
  return d;
}

// rule #18: inline-asm lgkmcnt needs sched_barrier(0) right after
#define LGKM_FENCE() do { asm volatile("s_waitcnt lgkmcnt(0)" ::: "memory"); \
                          __builtin_amdgcn_sched_barrier(0); } while (0)

// ---------------------------------------------------------------------------
// Projection GEMM: out = bf16( scale * (X.W + bias) ), M=8192 N=1024 K=1024
// 128x128xBK32 tiles, 4 waves, wave tile 64x64. Single-buffer LDS, 2 barriers
// per k-step (R1 structure). z==0 (q) folds log2e/8 into the output.
// ---------------------------------------------------------------------------
__global__ __launch_bounds__(256)
void proj_kernel(const float* __restrict__ x0, const float* __restrict__ x1, const float* __restrict__ x2,
                 const float* __restrict__ w0, const float* __restrict__ w1, const float* __restrict__ w2,
                 const float* __restrict__ b0, const float* __restrict__ b1, const float* __restrict__ b2,
                 u16* __restrict__ o0, u16* __restrict__ o1, u16* __restrict__ o2)
{
  // bijective XCD swizzle: nwg=1536 (%8==0)
  int p  = blockIdx.x + 8 * blockIdx.y + 512 * blockIdx.z;
  int wk = (p & 7) * 192 + (p >> 3);
  int nb = wk & 7, mb = (wk >> 3) & 63, z = wk >> 9;

  const float* X  = z == 0 ? x0 : (z == 1 ? x1 : x2);
  const float* W  = z == 0 ? w0 : (z == 1 ? w1 : w2);
  const float* BS = z == 0 ? b0 : (z == 1 ? b1 : b2);
  u16*         O  = z == 0 ? o0 : (z == 1 ? o1 : o2);
  const float  osc = (z == 0) ? QK_SCALE : 1.0f;

  const int t = threadIdx.x;
  const int lane = t & 63, wid = t >> 6;
  const int g = lane >> 4, ln = lane & 15;
  const int wm = wid >> 1, wn = wid & 1;
  const int mbase = mb * 128, nbase = nb * 128;

  // A: row-major, k-permuted so one b128 = one split-K fragment. stride 40 u16 (80B)
  __shared__ __align__(16) u16 As[128 * 40];
  // B: [nblk8][kblk2] tiles of [16k][16n], tile stride 272 u16 (544B) for tr-reads
  __shared__ __align__(16) u16 Bs[16 * 272];

  f32x4 acc[4][4];
#pragma unroll
  for (int i = 0; i < 4; ++i)
#pragma unroll
    for (int j = 0; j < 4; ++j) { acc[i][j][0]=0.f; acc[i][j][1]=0.f; acc[i][j][2]=0.f; acc[i][j][3]=0.f; }

  const int arow = t >> 3;                 // + 32*ps
  const int ak0  = (t & 7) * 4;            // 4-aligned k chunk
  const int ap   = 8 * ((ak0 & 15) >> 2) + 4 * (ak0 >> 4);  // k->perm position
  const int bkr  = t >> 5;                 // + 8*ps
  const int bnc  = (t & 31) * 4;
  const int bnblk = bnc >> 4, bncl = bnc & 15;

  const unsigned bs_base = (unsigned)(size_t)&Bs[0];

  for (int kb = 0; kb < 32; ++kb) {
    const int kbase = kb * 32;
    // stage A (fp32 -> bf16 via compiler cast, permuted columns)
#pragma unroll
    for (int ps = 0; ps < 4; ++ps) {
      int row = arow + 32 * ps;
      const float4 xv = *(const float4*)&X[(size_t)(mbase + row) * 1024 + kbase + ak0];
      bf16x4 sv = { f2bf_c(xv.x), f2bf_c(xv.y), f2bf_c(xv.z), f2bf_c(xv.w) };
      *(bf16x4*)&As[row * 40 + ap] = sv;
    }
    // stage B (fp32 -> bf16, k-major 16x16 tiles)
#pragma unroll
    for (int ps = 0; ps < 4; ++ps) {
      int kr = bkr + 8 * ps;
      const float4 wv = *(const float4*)&W[(size_t)(kbase + kr) * 1024 + nbase + bnc];
      bf16x4 sv = { f2bf_c(wv.x), f2bf_c(wv.y), f2bf_c(wv.z), f2bf_c(wv.w) };
      *(bf16x4*)&Bs[(bnblk * 2 + (kr >> 4)) * 272 + (kr & 15) * 16 + bncl] = sv;
    }
    __syncthreads();

    bf16x8 af[4];
#pragma unroll
    for (int mf = 0; mf < 4; ++mf)
      af[mf] = *(const bf16x8*)&As[(wm * 64 + mf * 16 + ln) * 40 + g * 8];

    bf16x8 bfv[4];
#pragma unroll
    for (int nf = 0; nf < 4; ++nf) {
      unsigned base = bs_base + (unsigned)(((wn * 4 + nf) * 2) * 544) + lane * 8;
      bf16x4 lo = ds_tr16(base);         // k 0..15
      bf16x4 hi = ds_tr16(base + 544);   // k 16..31
      bf16x8 bb;
      bb[0]=lo[0]; bb[1]=lo[1]; bb[2]=lo[2]; bb[3]=lo[3];
      bb[4]=hi[0]; bb[5]=hi[1]; bb[6]=hi[2]; bb[7]=hi[3];
      bfv[nf] = bb;
    }
    LGKM_FENCE();
#pragma unroll
    for (int mf = 0; mf < 4; ++mf)
#pragma unroll
      for (int nf = 0; nf < 4; ++nf)
        acc[mf][nf] = __builtin_amdgcn_mfma_f32_16x16x32_bf16(af[mf], bfv[nf], acc[mf][nf], 0, 0, 0);
    __syncthreads();
  }

  // epilogue: bias + scale + bf16 store
#pragma unroll
  for (int nf = 0; nf < 4; ++nf) {
    int n = nbase + wn * 64 + nf * 16 + ln;
    float bv = BS[n];
#pragma unroll
    for (int mf = 0; mf < 4; ++mf)
#pragma unroll
      for (int r = 0; r < 4; ++r) {
        int m = mbase + wm * 64 + mf * 16 + 4 * g + r;
        O[(size_t)m * 1024 + n] = (u16)f2bf_c((acc[mf][nf][r] + bv) * osc);
      }
  }
}

// ---------------------------------------------------------------------------
// Attention (unchanged): per block (b,h,qtile128), 4 waves x 32 q-rows, kv
// steps of 32. Swapped QK^T -> P feeds PV A-operand directly; max-free
// softmax (qh pre-scaled by log2e/8).
// ---------------------------------------------------------------------------
__global__ __launch_bounds__(256)
void attn_kernel(const u16* __restrict__ qh, const u16* __restrict__ kh, const u16* __restrict__ vh,
                 float* __restrict__ out)
{
  int p  = blockIdx.x + 16 * blockIdx.y + 256 * blockIdx.z;
  int wk = (p & 7) * 128 + (p >> 3);
  int qt = wk & 15, h = (wk >> 4) & 15, b = wk >> 8;

  const int t = threadIdx.x;
  const int lane = t & 63, wid = t >> 6;
  const int g = lane >> 4, ln = lane & 15;
  const size_t bS = (size_t)b * S_TOT;
  const int qwin = qt * 128 + wid * 32;

  __shared__ __align__(16) u16 Ks[32 * 72];
  __shared__ __align__(16) u16 Vs[8 * 272];

  bf16x8 qf[2][2];
#pragma unroll
  for (int nf = 0; nf < 2; ++nf) {
    const u16* qrow = &qh[(bS + qwin + nf * 16 + ln) * HD + h * 64];
#pragma unroll
    for (int kk = 0; kk < 2; ++kk) {
      bf16x4 lo = *(const bf16x4*)&qrow[kk * 32 + 4 * g];
      bf16x4 hi = *(const bf16x4*)&qrow[kk * 32 + 4 * g + 16];
      bf16x8 qq;
      qq[0]=lo[0]; qq[1]=lo[1]; qq[2]=lo[2]; qq[3]=lo[3];
      qq[4]=hi[0]; qq[5]=hi[1]; qq[6]=hi[2]; qq[7]=hi[3];
      qf[nf][kk] = qq;
    }
  }

  f32x4 o[2][4];
#pragma unroll
  for (int i = 0; i < 2; ++i)
#pragma unroll
    for (int j = 0; j < 4; ++j) { o[i][j][0]=0.f; o[i][j][1]=0.f; o[i][j][2]=0.f; o[i][j][3]=0.f; }
  float lsum[2] = {0.f, 0.f};

  const unsigned vs_base = (unsigned)(size_t)&Vs[0] + lane * 8;
  const int skv = t >> 4;
  const int sd0 = (t & 15) * 4;
  const int kpos = 32 * (sd0 >> 5) + 8 * ((sd0 & 15) >> 2) + 4 * ((sd0 >> 4) & 1);

  u16* ksw0 = &Ks[skv * 72 + kpos];
  u16* ksw1 = &Ks[(skv + 16) * 72 + kpos];
  u16* vsw0 = &Vs[(2 * (sd0 >> 4) + 0) * 272 + skv * 16 + (sd0 & 15)];
  u16* vsw1 = &Vs[(2 * (sd0 >> 4) + 1) * 272 + skv * 16 + (sd0 & 15)];
  const u16* kp = &kh[(bS + skv) * HD + h * 64 + sd0];
  const u16* vp = &vh[(bS + skv) * HD + h * 64 + sd0];

  for (int kvstep = 0; kvstep < 64; ++kvstep) {
    *(bf16x4*)ksw0 = *(const bf16x4*)kp;
    *(bf16x4*)ksw1 = *(const bf16x4*)(kp + (size_t)16 * HD);
    *(bf16x4*)vsw0 = *(const bf16x4*)vp;
    *(bf16x4*)vsw1 = *(const bf16x4*)(vp + (size_t)16 * HD);
    kp += (size_t)32 * HD; vp += (size_t)32 * HD;
    __syncthreads();

    bf16x8 kf[2][2];
#pragma unroll
    for (int mf = 0; mf < 2; ++mf)
#pragma unroll
      for (int kk = 0; kk < 2; ++kk)
        kf[mf][kk] = *(const bf16x8*)&Ks[(mf * 16 + ln) * 72 + kk * 32 + 8 * g];

    f32x4 sc[2][2];
#pragma unroll
    for (int mf = 0; mf < 2; ++mf)
#pragma unroll
      for (int nf = 0; nf < 2; ++nf) {
        f32x4 a; a[0]=0.f; a[1]=0.f; a[2]=0.f; a[3]=0.f;
#pragma unroll
        for (int kk = 0; kk < 2; ++kk)
          a = __builtin_amdgcn_mfma_f32_16x16x32_bf16(kf[mf][kk], qf[nf][kk], a, 0, 0, 0);
        sc[mf][nf] = a;
      }

    bf16x8 vf[4];
#pragma unroll
    for (int nf = 0; nf < 4; ++nf) {
      bf16x4 lo = ds_tr16(vs_base + (unsigned)((nf * 2) * 544));
      bf16x4 hi = ds_tr16(vs_base + (unsigned)((nf * 2 + 1) * 544));
      bf16x8 bb;
      bb[0]=lo[0]; bb[1]=lo[1]; bb[2]=lo[2]; bb[3]=lo[3];
      bb[4]=hi[0]; bb[5]=hi[1]; bb[6]=hi[2]; bb[7]=hi[3];
      vf[nf] = bb;
    }

    bf16x8 pa[2];
#pragma unroll
    for (int nf = 0; nf < 2; ++nf) {
      float pv[2][4];
#pragma unroll
      for (int mf = 0; mf < 2; ++mf)
#pragma unroll
        for (int r = 0; r < 4; ++r)
          pv[mf][r] = EXP2(sc[mf][nf][r]);
      float s0 = pv[0][0] + pv[0][1], s1 = pv[0][2] + pv[0][3];
      float s2 = pv[1][0] + pv[1][1], s3 = pv[1][2] + pv[1][3];
      lsum[nf] += (s0 + s1) + (s2 + s3);
      union { u32x4 u; bf16x8 b; } pk;
      pk.u[0] = cvt_pk_bf16(pv[0][0], pv[0][1]);
      pk.u[1] = cvt_pk_bf16(pv[0][2], pv[0][3]);
      pk.u[2] = cvt_pk_bf16(pv[1][0], pv[1][1]);
      pk.u[3] = cvt_pk_bf16(pv[1][2], pv[1][3]);
      pa[nf] = pk.b;
    }

    LGKM_FENCE();
#pragma unroll
    for (int mq = 0; mq < 2; ++mq)
#pragma unroll
      for (int nf = 0; nf < 4; ++nf)
        o[mq][nf] = __builtin_amdgcn_mfma_f32_16x16x32_bf16(pa[mq], vf[nf], o[mq][nf], 0, 0, 0);
    __syncthreads();
  }

#pragma unroll
  for (int nf = 0; nf < 2; ++nf) {
    lsum[nf] += __shfl_xor(lsum[nf], 16, 64);
    lsum[nf] += __shfl_xor(lsum[nf], 32, 64);
  }

#pragma unroll
  for (int mq = 0; mq < 2; ++mq)
#pragma unroll
    for (int r = 0; r < 4; ++r) {
      int src = (lane & 48) | (4 * g + r);
      float inv = 1.0f / __shfl(lsum[mq], src, 64);
      int qrow = qwin + mq * 16 + 4 * g + r;
#pragma unroll
      for (int nf = 0; nf < 4; ++nf)
        out[(bS + qrow) * HD + h * 64 + nf * 16 + ln] = o[mq][nf][r] * inv;
    }
}

extern "C" void kernel_launch(void* const* d_in, const int* in_sizes, int n_in,
                              void* d_out, int out_size, void* d_ws, size_t ws_size,
                              hipStream_t stream) {
  const float* q  = (const float*)d_in[0];
  const float* k  = (const float*)d_in[1];
  const float* v  = (const float*)d_in[2];
  const float* Wq = (const float*)d_in[3];
  const float* bq = (const float*)d_in[4];
  const float* Wk = (const float*)d_in[5];
  const float* bk = (const float*)d_in[6];
  const float* Wv = (const float*)d_in[7];
  const float* bv = (const float*)d_in[8];
  float* out = (float*)d_out;

  u16* qh = (u16*)d_ws;
  u16* kh = qh + (size_t)8192 * 1024;
  u16* vh = kh + (size_t)8192 * 1024;

  proj_kernel<<<dim3(8, 64, 3), 256, 0, stream>>>(q, k, v, Wq, Wk, Wv, bq, bk, bv, qh, kh, vh);
  attn_kernel<<<dim3(16, 16, 4), 256, 0, stream>>>(qh, kh, vh, out);
}